// Round 1
// baseline (399.972 us; speedup 1.0000x reference)
//
#include <hip/hip_runtime.h>

#define IN_F   8192
#define OUT_F  14336
#define M_TOK  64
#define KPI    4096              // packed int32 per weight row
#define BN     128               // n per block (4 waves x 32)
#define NBLK   (OUT_F / BN)      // 112
#define KSPLIT 16
#define KCHUNK (IN_F / KSPLIT)   // 512 k per block
#define PSTRIDE (M_TOK * OUT_F)  // floats per k-split partial = 917504

typedef __attribute__((ext_vector_type(8)))  short bf16x8;   // 8 bf16 (4 VGPRs)
typedef __attribute__((ext_vector_type(16))) float f32x16;   // 32x32 MFMA C/D frag

__device__ __forceinline__ unsigned short f2bf_rne(float f) {
    unsigned u = __builtin_bit_cast(unsigned, f);
    u += 0x7FFFu + ((u >> 16) & 1u);
    return (unsigned short)(u >> 16);
}

// Prep: x fp32 -> bf16 workspace (out is fully written by qlin_reduce).
__global__ __launch_bounds__(256) void qlin_prep(const float* __restrict__ x,
                                                 unsigned short* __restrict__ xb) {
    int gid = blockIdx.x * 256 + threadIdx.x;   // 131072 float4
    float4 v = reinterpret_cast<const float4*>(x)[gid];
    ushort4 o;
    o.x = f2bf_rne(v.x);
    o.y = f2bf_rne(v.y);
    o.z = f2bf_rne(v.z);
    o.w = f2bf_rne(v.w);
    reinterpret_cast<ushort4*>(xb)[gid] = o;
}

// One packed int32 (byte: lo nibble = even k, hi nibble = odd k) -> two bf16
// bit-patterns in one dword. Ints in [-8,7] are exact in bf16.
__device__ __forceinline__ int unpack2_bf16(int v) {
    int q0 = ((int)((unsigned)v << 28)) >> 28;
    int q1 = ((int)((unsigned)v << 24)) >> 28;
    unsigned u0 = __builtin_bit_cast(unsigned, (float)q0);
    unsigned u1 = __builtin_bit_cast(unsigned, (float)q1);
    return (int)((u0 >> 16) | (u1 & 0xFFFF0000u));
}

__device__ __forceinline__ bf16x8 unpack_b(int4 wv) {
    int4 pk;
    pk.x = unpack2_bf16(wv.x);
    pk.y = unpack2_bf16(wv.y);
    pk.z = unpack2_bf16(wv.z);
    pk.w = unpack2_bf16(wv.w);
    return __builtin_bit_cast(bf16x8, pk);
}

// Direct-to-register streaming GEMM (no LDS, no barriers).
// This op is GEMV-shaped (M=64): the prior LDS-staged version moved 72 KB
// through the LDS pipe per 24 KB of weights and drained vmcnt(0) at two
// barriers per 64-k step -> ~1 TB/s effective. Here each lane streams its
// own weight row: MFMA B-frag (n=lane&31, k-half=lane>>5, 8 k) is exactly
// one dwordx4 from global; rows are consumed sequentially (32 B/row/step)
// so every 128-B line is fully used via L1/L2. A-frags read the 1 MB bf16
// x image straight from L2. Offsets within the 512-k chunk are immediates
// after unrolling -> minimal address VALU; compiler pipelines loads with
// counted vmcnt. Grid 112 x 16 = 1792 blocks = exactly 7/CU.
__global__ __launch_bounds__(256) void qlin_gemm(const unsigned short* __restrict__ xb,
                                                 const int* __restrict__ wp,
                                                 const float* __restrict__ scales,
                                                 float* __restrict__ part) {
    const int tid  = threadIdx.x;
    const int wave = tid >> 6;
    const int lane = tid & 63;
    const int tp   = lane & 31;   // 32x32 frag: n (B) / m (A) / col (C)
    const int qp   = lane >> 5;   // 32x32 frag: k-half ; C/D row offset 4*qp

    const int nblk = blockIdx.x % NBLK;
    const int kblk = blockIdx.x / NBLK;
    const int n0   = nblk * BN;
    const int n    = n0 + wave * 32 + tp;  // this lane's weight row
    const int kb   = kblk * KCHUNK;        // k base (elements)

    // per 16-k step s: idx = s*2 + qp
    //   w:  int4 at  wp + n*KPI + kb/2 + idx*4   (4 int32 = 8 k-values)
    //   x:  bf16x8 at xb + m*IN_F + kb + idx*8   (8 bf16)
    const int4*   wrow = reinterpret_cast<const int4*>(wp + (size_t)n * KPI + (kb >> 1));
    const bf16x8* x0   = reinterpret_cast<const bf16x8*>(xb + (size_t)tp * IN_F + kb);
    const bf16x8* x1   = reinterpret_cast<const bf16x8*>(xb + (size_t)(32 + tp) * IN_F + kb);

    f32x16 acc0 = {0.f,0.f,0.f,0.f,0.f,0.f,0.f,0.f,0.f,0.f,0.f,0.f,0.f,0.f,0.f,0.f};
    f32x16 acc1 = acc0;

#pragma unroll 4
    for (int s = 0; s < KCHUNK / 16; ++s) {
        const int idx = s * 2 + qp;
        int4   wv = wrow[idx];
        bf16x8 a0 = x0[idx];
        bf16x8 a1 = x1[idx];
        bf16x8 b  = unpack_b(wv);
        acc0 = __builtin_amdgcn_mfma_f32_32x32x16_bf16(a0, b, acc0, 0, 0, 0);
        acc1 = __builtin_amdgcn_mfma_f32_32x32x16_bf16(a1, b, acc1, 0, 0, 0);
    }

    // ---- epilogue: C/D layout col=tp, row=(reg&3)+8*(reg>>2)+4*qp; plain stores ----
    const float sc = scales[n];
    float* p = part + (size_t)kblk * PSTRIDE;
#pragma unroll
    for (int reg = 0; reg < 16; ++reg) {
        int m = (reg & 3) + 8 * (reg >> 2) + 4 * qp;
        p[(size_t)m        * OUT_F + n] = acc0[reg] * sc;
        p[(size_t)(32 + m) * OUT_F + n] = acc1[reg] * sc;
    }
}

// out[m][n] = bias[n] + sum over 16 k-split partials. 229376 float4 threads.
__global__ __launch_bounds__(256) void qlin_reduce(const float* __restrict__ part,
                                                   const float* __restrict__ bias,
                                                   float* __restrict__ out) {
    int g = blockIdx.x * 256 + threadIdx.x;            // 0..229375
    float4 acc = reinterpret_cast<const float4*>(bias)[g % (OUT_F / 4)];
#pragma unroll
    for (int s = 0; s < KSPLIT; ++s) {
        float4 v = reinterpret_cast<const float4*>(part + (size_t)s * PSTRIDE)[g];
        acc.x += v.x; acc.y += v.y; acc.z += v.z; acc.w += v.w;
    }
    reinterpret_cast<float4*>(out)[g] = acc;
}

extern "C" void kernel_launch(void* const* d_in, const int* in_sizes, int n_in,
                              void* d_out, int out_size, void* d_ws, size_t ws_size,
                              hipStream_t stream) {
    const float* x    = (const float*)d_in[0];
    const int*   wp   = (const int*)d_in[1];
    const float* sc   = (const float*)d_in[2];
    const float* bias = (const float*)d_in[3];
    float* out = (float*)d_out;

    unsigned short* xb   = (unsigned short*)d_ws;                   // 1 MB
    float*          part = (float*)((char*)d_ws + (1 << 20));       // 16 x 3.67 MB

    qlin_prep<<<(M_TOK * IN_F) / 4 / 256, 256, 0, stream>>>(x, xb);
    qlin_gemm<<<NBLK * KSPLIT, 256, 0, stream>>>(xb, wp, sc, part);
    qlin_reduce<<<(M_TOK * OUT_F) / 4 / 256, 256, 0, stream>>>(part, bias, out);
}

// Round 3
// 354.060 us; speedup vs baseline: 1.1297x; 1.1297x over previous
//
#include <hip/hip_runtime.h>

#define IN_F   8192
#define OUT_F  14336
#define M_TOK  64
#define KPI    4096              // packed int32 per weight row
#define BN     128               // n per block (4 waves x 32)
#define NBLK   (OUT_F / BN)      // 112
#define KSPLIT 8
#define KCHUNK (IN_F / KSPLIT)   // 1024 k per block
#define BK     64                // k per staging step
#define NSTEP  (KCHUNK / BK)     // 16
#define PSTRIDE (M_TOK * OUT_F)  // floats per k-split partial = 917504

typedef __attribute__((ext_vector_type(8)))  short bf16x8;   // 8 bf16 (4 VGPRs)
typedef __attribute__((ext_vector_type(16))) float f32x16;   // 32x32 MFMA C/D frag

__device__ __forceinline__ unsigned short f2bf_rne(float f) {
    unsigned u = __builtin_bit_cast(unsigned, f);
    u += 0x7FFFu + ((u >> 16) & 1u);
    return (unsigned short)(u >> 16);
}

// Prep: x fp32 -> bf16 workspace (out is fully written by qlin_reduce).
__global__ __launch_bounds__(256) void qlin_prep(const float* __restrict__ x,
                                                 unsigned short* __restrict__ xb) {
    int gid = blockIdx.x * 256 + threadIdx.x;   // 131072 float4
    float4 v = reinterpret_cast<const float4*>(x)[gid];
    ushort4 o;
    o.x = f2bf_rne(v.x);
    o.y = f2bf_rne(v.y);
    o.z = f2bf_rne(v.z);
    o.w = f2bf_rne(v.w);
    reinterpret_cast<ushort4*>(xb)[gid] = o;
}

// One packed int32 (byte: lo nibble = even k, hi nibble = odd k) -> two bf16
// bit-patterns in one dword. Ints in [-8,7] are exact in bf16.
__device__ __forceinline__ int unpack2_bf16(int v) {
    int q0 = ((int)((unsigned)v << 28)) >> 28;
    int q1 = ((int)((unsigned)v << 24)) >> 28;
    unsigned u0 = __builtin_bit_cast(unsigned, (float)q0);
    unsigned u1 = __builtin_bit_cast(unsigned, (float)q1);
    return (int)((u0 >> 16) | (u1 & 0xFFFF0000u));
}

__device__ __forceinline__ bf16x8 unpack_b(int4 wv) {
    int4 pk;
    pk.x = unpack2_bf16(wv.x);
    pk.y = unpack2_bf16(wv.y);
    pk.z = unpack2_bf16(wv.z);
    pk.w = unpack2_bf16(wv.w);
    return __builtin_bit_cast(bf16x8, pk);
}

// async 16-B global -> LDS (LDS dest = wave-uniform base + lane*16, fixed by HW).
__device__ __forceinline__ void gload_lds16(const void* g, void* l) {
    __builtin_amdgcn_global_load_lds(
        (const __attribute__((address_space(1))) unsigned int*)g,
        (__attribute__((address_space(3))) unsigned int*)l,
        16, 0, 0);
}

// Coalesced LDS-staged GEMM with a T3/T4 2-phase pipeline (counted vmcnt,
// raw barriers, never vmcnt(0) in the main loop).
//
// Why not direct-to-register: lane stride for the MFMA B/A frags is 16 KB,
// so every register load was a 32-line scatter; per-CU live-line set ~340 KB
// thrashed the 32 KB L1 -> each 16-B load became a 128-B L2 fill (~8x
// amplification, ~2.8 GB L1<->L2 per pass) -> 157 us with all pipes idle.
// gload_lds fetches each 128-B line exactly once, 1 KB/instruction.
//
// Why not __syncthreads(): the compiler drains vmcnt(0) before s_barrier,
// exposing full HBM latency every 64-k step (the old 355-us convoy).
// Here: 2-deep double buffer; per wave each stage = 6 gload_lds (4 w + 2 x);
// in-loop wait is vmcnt(6) so the next tile's loads stay in flight across
// both barriers. Bank-conflict-free via the proven global-side swizzle:
// LDS slot (row r, chunk cl) holds global chunk cl^(r&7).
__global__ __launch_bounds__(256) void qlin_gemm(const unsigned short* __restrict__ xb,
                                                 const int* __restrict__ wp,
                                                 const float* __restrict__ scales,
                                                 float* __restrict__ part) {
    __shared__ int            wlds[2][BN * (BK / 2)];   // 2 x 16 KB
    __shared__ unsigned short xlds[2][M_TOK * BK];      // 2 x  8 KB  (48 KB -> 3 blocks/CU)

    const int tid  = threadIdx.x;
    const int wave = tid >> 6;
    const int lane = tid & 63;
    const int tp   = lane & 31;   // 32x32 frag: n (B) / m (A) / col (C)
    const int qp   = lane >> 5;   // 32x32 frag: k-half ; C/D row offset 4*qp

    const int nblk = blockIdx.x % NBLK;
    const int kblk = blockIdx.x / NBLK;
    const int n0   = nblk * BN;
    const int kb   = kblk * KCHUNK;        // k base (elements)

    f32x16 acc0 = {0.f,0.f,0.f,0.f,0.f,0.f,0.f,0.f,0.f,0.f,0.f,0.f,0.f,0.f,0.f,0.f};
    f32x16 acc1 = acc0;

    // ---- stage tile t into buffer b: 16 instrs w + 8 instrs x per block ----
#define STAGE(b, t) do {                                                           \
    _Pragma("unroll")                                                              \
    for (int j = 0; j < 4; ++j) {                                                  \
        int li = (wave * 4 + j) * 64 + lane;       /* slot 0..1023 */              \
        int r  = li >> 3;                          /* weight row 0..127 */         \
        int cg = (li & 7) ^ (r & 7);               /* global chunk (swizzled) */   \
        const int* gp = wp + (size_t)(n0 + r) * KPI + (kb >> 1) + (t) * (BK / 2) + cg * 4; \
        gload_lds16(gp, (char*)&wlds[b][0] + (size_t)li * 16);                     \
    }                                                                              \
    _Pragma("unroll")                                                              \
    for (int j = 0; j < 2; ++j) {                                                  \
        int li = (wave * 2 + j) * 64 + lane;       /* slot 0..511 */               \
        int r  = li >> 3;                          /* m row 0..63 */               \
        int cg = (li & 7) ^ (r & 7);                                               \
        const unsigned short* gp = xb + (size_t)r * IN_F + kb + (t) * BK + cg * 8; \
        gload_lds16(gp, (char*)&xlds[b][0] + (size_t)li * 16);                     \
    }                                                                              \
} while (0)

#define COMPUTE(b) do {                                                            \
    _Pragma("unroll")                                                              \
    for (int kf = 0; kf < 4; ++kf) {                                               \
        const int c = kf * 2 + qp;                 /* 16-B chunk within row */     \
        const int R = wave * 32 + tp;                                              \
        int4 wv = *reinterpret_cast<const int4*>(                                  \
            (const char*)&wlds[b][0] + (size_t)(R * 8 + (c ^ (R & 7))) * 16);      \
        bf16x8 bb = unpack_b(wv);                                                  \
        bf16x8 a0 = *reinterpret_cast<const bf16x8*>(                              \
            (const char*)&xlds[b][0] + (size_t)(tp * 8 + (c ^ (tp & 7))) * 16);    \
        bf16x8 a1 = *reinterpret_cast<const bf16x8*>(                              \
            (const char*)&xlds[b][0] + (size_t)((32 + tp) * 8 + (c ^ (tp & 7))) * 16); \
        acc0 = __builtin_amdgcn_mfma_f32_32x32x16_bf16(a0, bb, acc0, 0, 0, 0);     \
        acc1 = __builtin_amdgcn_mfma_f32_32x32x16_bf16(a1, bb, acc1, 0, 0, 0);     \
    }                                                                              \
} while (0)

    // prologue: 2-deep prefetch (12 vmem ops/wave in flight)
    STAGE(0, 0);
    STAGE(1, 1);

    for (int t = 0; t < NSTEP - 1; ++t) {
        const int cur = t & 1;
        // tile t complete when only tile t+1's 6 ops remain outstanding
        asm volatile("s_waitcnt vmcnt(6)" ::: "memory");
        __builtin_amdgcn_sched_barrier(0);
        __builtin_amdgcn_s_barrier();
        __builtin_amdgcn_sched_barrier(0);
        COMPUTE(cur);
        // every ds_read is consumed by an MFMA above (lgkm waits emitted by
        // compiler), so after this barrier buf[cur] is dead for all waves.
        __builtin_amdgcn_sched_barrier(0);
        __builtin_amdgcn_s_barrier();
        __builtin_amdgcn_sched_barrier(0);
        if (t + 2 < NSTEP) STAGE(cur, t + 2);
    }
    // peeled final tile: must fully drain (its 6 ops are the newest)
    asm volatile("s_waitcnt vmcnt(0)" ::: "memory");
    __builtin_amdgcn_sched_barrier(0);
    __builtin_amdgcn_s_barrier();
    __builtin_amdgcn_sched_barrier(0);
    COMPUTE((NSTEP - 1) & 1);

    // ---- epilogue: C/D layout col=tp, row=(reg&3)+8*(reg>>2)+4*qp; plain stores ----
    const int   n  = n0 + wave * 32 + tp;
    const float sc = scales[n];
    float* p = part + (size_t)kblk * PSTRIDE;
#pragma unroll
    for (int reg = 0; reg < 16; ++reg) {
        int m = (reg & 3) + 8 * (reg >> 2) + 4 * qp;
        p[(size_t)m        * OUT_F + n] = acc0[reg] * sc;
        p[(size_t)(32 + m) * OUT_F + n] = acc1[reg] * sc;
    }
#undef STAGE
#undef COMPUTE
}

// out[m][n] = bias[n] + sum over KSPLIT partials. 2-D grid avoids the
// non-pow2 modulo: blockIdx.x covers OUT_F/1024=14, blockIdx.y = m.
__global__ __launch_bounds__(256) void qlin_reduce(const float* __restrict__ part,
                                                   const float* __restrict__ bias,
                                                   float* __restrict__ out) {
    const int    nq   = blockIdx.x * 256 + threadIdx.x;   // 0..3583 (float4 index in n)
    const int    m    = blockIdx.y;
    const size_t base = (size_t)m * (OUT_F / 4) + nq;
    float4 acc = reinterpret_cast<const float4*>(bias)[nq];
#pragma unroll
    for (int s = 0; s < KSPLIT; ++s) {
        float4 v = reinterpret_cast<const float4*>(part)[(size_t)s * (PSTRIDE / 4) + base];
        acc.x += v.x; acc.y += v.y; acc.z += v.z; acc.w += v.w;
    }
    reinterpret_cast<float4*>(out)[base] = acc;
}

extern "C" void kernel_launch(void* const* d_in, const int* in_sizes, int n_in,
                              void* d_out, int out_size, void* d_ws, size_t ws_size,
                              hipStream_t stream) {
    const float* x    = (const float*)d_in[0];
    const int*   wp   = (const int*)d_in[1];
    const float* sc   = (const float*)d_in[2];
    const float* bias = (const float*)d_in[3];
    float* out = (float*)d_out;

    unsigned short* xb   = (unsigned short*)d_ws;                   // 1 MB
    float*          part = (float*)((char*)d_ws + (1 << 20));       // 8 x 3.67 MB

    qlin_prep<<<(M_TOK * IN_F) / 4 / 256, 256, 0, stream>>>(x, xb);
    qlin_gemm<<<NBLK * KSPLIT, 256, 0, stream>>>(xb, wp, sc, part);
    qlin_reduce<<<dim3(OUT_F / 4 / 256, M_TOK), 256, 0, stream>>>(part, bias, out);
}

// Round 10
// 346.158 us; speedup vs baseline: 1.1555x; 1.0228x over previous
//
#include <hip/hip_runtime.h>

#define IN_F   8192
#define OUT_F  14336
#define M_TOK  64
#define KPI    4096              // packed int32 per weight row
#define BN     128               // n per block (4 waves x 32)
#define NBLK   (OUT_F / BN)      // 112
#define KSPLIT 16
#define KCHUNK (IN_F / KSPLIT)   // 512 k per block
#define BK     64                // k per staging step
#define NSTEP  (KCHUNK / BK)     // 8
#define XB_BLOCKS ((M_TOK * IN_F) / 4 / 256)   // 512
#define OI_BLOCKS ((M_TOK * OUT_F) / 4 / 256)  // 896

typedef __attribute__((ext_vector_type(8)))  short bf16x8;   // 8 bf16 (4 VGPRs)
typedef __attribute__((ext_vector_type(16))) float f32x16;   // 32x32 MFMA C/D frag

__device__ __forceinline__ unsigned short f2bf_rne(float f) {
    unsigned u = __builtin_bit_cast(unsigned, f);
    u += 0x7FFFu + ((u >> 16) & 1u);
    return (unsigned short)(u >> 16);
}

// Combined setup: blocks [0,512) convert x fp32 -> bf16; blocks [512,1408)
// initialize out[m][n] = bias[n] (gemm then atomically accumulates into out,
// replacing the separate reduce kernel + 29 MB partial read entirely).
__global__ __launch_bounds__(256) void qlin_setup(const float* __restrict__ x,
                                                  const float* __restrict__ bias,
                                                  unsigned short* __restrict__ xb,
                                                  float* __restrict__ out) {
    const int b   = blockIdx.x;
    const int tid = threadIdx.x;
    if (b < XB_BLOCKS) {
        int gid = b * 256 + tid;                       // 131072 float4
        float4 v = reinterpret_cast<const float4*>(x)[gid];
        ushort4 o;
        o.x = f2bf_rne(v.x);
        o.y = f2bf_rne(v.y);
        o.z = f2bf_rne(v.z);
        o.w = f2bf_rne(v.w);
        reinterpret_cast<ushort4*>(xb)[gid] = o;
    } else {
        int idx = (b - XB_BLOCKS) * 256 + tid;         // 0..229375 float4
        int nq  = idx % (OUT_F / 4);                   // compiler magic-div
        reinterpret_cast<float4*>(out)[idx] =
            reinterpret_cast<const float4*>(bias)[nq];
    }
}

// One packed int32 (byte: lo nibble = even k, hi nibble = odd k) -> two bf16
// bit-patterns in one dword. Ints in [-8,7] are exact in bf16.
__device__ __forceinline__ int unpack2_bf16(int v) {
    int q0 = ((int)((unsigned)v << 28)) >> 28;
    int q1 = ((int)((unsigned)v << 24)) >> 28;
    unsigned u0 = __builtin_bit_cast(unsigned, (float)q0);
    unsigned u1 = __builtin_bit_cast(unsigned, (float)q1);
    return (int)((u0 >> 16) | (u1 & 0xFFFF0000u));
}

__device__ __forceinline__ bf16x8 unpack_b(int4 wv) {
    int4 pk;
    pk.x = unpack2_bf16(wv.x);
    pk.y = unpack2_bf16(wv.y);
    pk.z = unpack2_bf16(wv.z);
    pk.w = unpack2_bf16(wv.w);
    return __builtin_bit_cast(bf16x8, pk);
}

// async 16-B global -> LDS (LDS dest = wave-uniform base + lane*16, fixed by HW).
__device__ __forceinline__ void gload_lds16(const void* g, void* l) {
    __builtin_amdgcn_global_load_lds(
        (const __attribute__((address_space(1))) unsigned int*)g,
        (__attribute__((address_space(3))) unsigned int*)l,
        16, 0, 0);
}

// Coalesced LDS-staged GEMM, T3/T4 2-phase pipeline (counted vmcnt(6), raw
// barriers, never vmcnt(0) in the main loop) — K-loop structure verified in
// round 3 (gemm dropped below the 139 us fill, i.e. <139 from 157).
// Changes this round (epilogue/grid only, K-loop untouched):
//  - KSPLIT 8->16: 1792 blocks (3 resident/CU, ~2.3 fine rounds, smaller tail)
//  - epilogue: unsafeAtomicAdd (HW global_atomic_add_f32) of scale*acc into
//    out (pre-filled with bias by qlin_setup) — no partials, no reduce kernel.
//  - workspace shrinks 30 MB -> 1 MB (re-poison fill cost scales with ws).
__global__ __launch_bounds__(256) void qlin_gemm(const unsigned short* __restrict__ xb,
                                                 const int* __restrict__ wp,
                                                 const float* __restrict__ scales,
                                                 float* __restrict__ out) {
    __shared__ int            wlds[2][BN * (BK / 2)];   // 2 x 16 KB
    __shared__ unsigned short xlds[2][M_TOK * BK];      // 2 x  8 KB  (48 KB -> 3 blocks/CU)

    const int tid  = threadIdx.x;
    const int wave = tid >> 6;
    const int lane = tid & 63;
    const int tp   = lane & 31;   // 32x32 frag: n (B) / m (A) / col (C)
    const int qp   = lane >> 5;   // 32x32 frag: k-half ; C/D row offset 4*qp

    const int nblk = blockIdx.x % NBLK;
    const int kblk = blockIdx.x / NBLK;
    const int n0   = nblk * BN;
    const int kb   = kblk * KCHUNK;        // k base (elements)

    f32x16 acc0 = {0.f,0.f,0.f,0.f,0.f,0.f,0.f,0.f,0.f,0.f,0.f,0.f,0.f,0.f,0.f,0.f};
    f32x16 acc1 = acc0;

    // ---- stage tile t into buffer b: 16 instrs w + 8 instrs x per block ----
#define STAGE(b, t) do {                                                           \
    _Pragma("unroll")                                                              \
    for (int j = 0; j < 4; ++j) {                                                  \
        int li = (wave * 4 + j) * 64 + lane;       /* slot 0..1023 */              \
        int r  = li >> 3;                          /* weight row 0..127 */         \
        int cg = (li & 7) ^ (r & 7);               /* global chunk (swizzled) */   \
        const int* gp = wp + (size_t)(n0 + r) * KPI + (kb >> 1) + (t) * (BK / 2) + cg * 4; \
        gload_lds16(gp, (char*)&wlds[b][0] + (size_t)li * 16);                     \
    }                                                                              \
    _Pragma("unroll")                                                              \
    for (int j = 0; j < 2; ++j) {                                                  \
        int li = (wave * 2 + j) * 64 + lane;       /* slot 0..511 */               \
        int r  = li >> 3;                          /* m row 0..63 */               \
        int cg = (li & 7) ^ (r & 7);                                               \
        const unsigned short* gp = xb + (size_t)r * IN_F + kb + (t) * BK + cg * 8; \
        gload_lds16(gp, (char*)&xlds[b][0] + (size_t)li * 16);                     \
    }                                                                              \
} while (0)

#define COMPUTE(b) do {                                                            \
    _Pragma("unroll")                                                              \
    for (int kf = 0; kf < 4; ++kf) {                                               \
        const int c = kf * 2 + qp;                 /* 16-B chunk within row */     \
        const int R = wave * 32 + tp;                                              \
        int4 wv = *reinterpret_cast<const int4*>(                                  \
            (const char*)&wlds[b][0] + (size_t)(R * 8 + (c ^ (R & 7))) * 16);      \
        bf16x8 bb = unpack_b(wv);                                                  \
        bf16x8 a0 = *reinterpret_cast<const bf16x8*>(                              \
            (const char*)&xlds[b][0] + (size_t)(tp * 8 + (c ^ (tp & 7))) * 16);    \
        bf16x8 a1 = *reinterpret_cast<const bf16x8*>(                              \
            (const char*)&xlds[b][0] + (size_t)((32 + tp) * 8 + (c ^ (tp & 7))) * 16); \
        acc0 = __builtin_amdgcn_mfma_f32_32x32x16_bf16(a0, bb, acc0, 0, 0, 0);     \
        acc1 = __builtin_amdgcn_mfma_f32_32x32x16_bf16(a1, bb, acc1, 0, 0, 0);     \
    }                                                                              \
} while (0)

    // prologue: 2-deep prefetch (12 vmem ops/wave in flight)
    STAGE(0, 0);
    STAGE(1, 1);

    for (int t = 0; t < NSTEP - 1; ++t) {
        const int cur = t & 1;
        // tile t complete when only tile t+1's 6 ops remain outstanding
        asm volatile("s_waitcnt vmcnt(6)" ::: "memory");
        __builtin_amdgcn_sched_barrier(0);
        __builtin_amdgcn_s_barrier();
        __builtin_amdgcn_sched_barrier(0);
        COMPUTE(cur);
        // every ds_read is consumed by an MFMA above (lgkm waits emitted by
        // compiler), so after this barrier buf[cur] is dead for all waves.
        __builtin_amdgcn_sched_barrier(0);
        __builtin_amdgcn_s_barrier();
        __builtin_amdgcn_sched_barrier(0);
        if (t + 2 < NSTEP) STAGE(cur, t + 2);
    }
    // peeled final tile: must fully drain (its 6 ops are the newest)
    asm volatile("s_waitcnt vmcnt(0)" ::: "memory");
    __builtin_amdgcn_sched_barrier(0);
    __builtin_amdgcn_s_barrier();
    __builtin_amdgcn_sched_barrier(0);
    COMPUTE((NSTEP - 1) & 1);

    // ---- epilogue: C/D layout col=tp, row=(reg&3)+8*(reg>>2)+4*qp ----
    // out was pre-filled with bias; accumulate scale*acc with HW f32 atomics
    // (device-scope, order-independent across the 16 k-splits).
    const int   n  = n0 + wave * 32 + tp;
    const float sc = scales[n];
#pragma unroll
    for (int reg = 0; reg < 16; ++reg) {
        int m = (reg & 3) + 8 * (reg >> 2) + 4 * qp;
        unsafeAtomicAdd(out + (size_t)m        * OUT_F + n, acc0[reg] * sc);
        unsafeAtomicAdd(out + (size_t)(32 + m) * OUT_F + n, acc1[reg] * sc);
    }
#undef STAGE
#undef COMPUTE
}

extern "C" void kernel_launch(void* const* d_in, const int* in_sizes, int n_in,
                              void* d_out, int out_size, void* d_ws, size_t ws_size,
                              hipStream_t stream) {
    const float* x    = (const float*)d_in[0];
    const int*   wp   = (const int*)d_in[1];
    const float* sc   = (const float*)d_in[2];
    const float* bias = (const float*)d_in[3];
    float* out = (float*)d_out;

    unsigned short* xb = (unsigned short*)d_ws;   // 1 MB (only ws use)

    qlin_setup<<<XB_BLOCKS + OI_BLOCKS, 256, 0, stream>>>(x, bias, xb, out);
    qlin_gemm<<<NBLK * KSPLIT, 256, 0, stream>>>(xb, wp, sc, out);
}